// Round 7
// baseline (434.864 us; speedup 1.0000x reference)
//
#include <hip/hip_runtime.h>
#include <cstdint>
#include <cstddef>

// GraphSAGE 3-layer, mean aggregation.
// R6: gemm was latency-serialized per k-step (MfmaUtil 23%, all layers equal
// time regardless of K; occupancy 23% = VGPR cap at 2 waves/SIMD, acc in AGPRs).
// Now: double-buffered A LDS (2x8KB) + software prefetch of A[s+1] (global->reg)
// and W[s+1] (global->reg, ping-pong register sets, explicit 2-unroll) issued
// BEFORE the 48 MFMAs of step s; convert+ds_write after; ONE barrier per step.
// Reg loads survive __syncthreads -> A/W latency hides under MFMA.
// Scan (R3), bf16 gather agg (R4), split-bf16 MFMA math (R2) unchanged.

typedef __bf16 bf16x8 __attribute__((ext_vector_type(8)));
typedef __bf16 bf16x4 __attribute__((ext_vector_type(4)));
typedef float  f32x4  __attribute__((ext_vector_type(4)));

static inline size_t align_up(size_t x, size_t a) { return (x + a - 1) / a * a; }

__global__ void deg_kernel(const int* __restrict__ dst, int* __restrict__ deg, int E) {
    int i = blockIdx.x * blockDim.x + threadIdx.x;
    if (i < E) atomicAdd(&deg[dst[i]], 1);
}

// ---- 3-phase scan: deg -> rowptr (exclusive), cursor, inv_deg ----
__global__ void scan_a(const int* __restrict__ deg, int* __restrict__ blocksums, int n) {
    __shared__ int ts[256];
    int t = threadIdx.x;
    int base = blockIdx.x * 1024 + t * 4;
    int s = 0;
    #pragma unroll
    for (int j = 0; j < 4; ++j) if (base + j < n) s += deg[base + j];
    ts[t] = s;
    __syncthreads();
    #pragma unroll
    for (int off = 128; off >= 1; off >>= 1) {
        if (t < off) ts[t] += ts[t + off];
        __syncthreads();
    }
    if (t == 0) blocksums[blockIdx.x] = ts[0];
}

__global__ void scan_b(const int* __restrict__ blocksums, int* __restrict__ blockoff,
                       int NB, int* __restrict__ rowptr_n) {
    __shared__ int ts[256];
    int t = threadIdx.x;
    int v = (t < NB) ? blocksums[t] : 0;
    ts[t] = v;
    __syncthreads();
    for (int off = 1; off < 256; off <<= 1) {
        int u = (t >= off) ? ts[t - off] : 0;
        __syncthreads();
        ts[t] += u;
        __syncthreads();
    }
    if (t < NB) blockoff[t] = ts[t] - v;
    if (t == 255) *rowptr_n = ts[255];
}

__global__ void scan_c(const int* __restrict__ deg, const int* __restrict__ blockoff,
                       int* __restrict__ rowptr, int* __restrict__ cursor,
                       float* __restrict__ inv_deg, int n) {
    __shared__ int ts[256];
    int t = threadIdx.x;
    int base = blockIdx.x * 1024 + t * 4;
    int d[4];
    int s = 0;
    #pragma unroll
    for (int j = 0; j < 4; ++j) {
        d[j] = (base + j < n) ? deg[base + j] : 0;
        s += d[j];
    }
    ts[t] = s;
    __syncthreads();
    for (int off = 1; off < 256; off <<= 1) {
        int u = (t >= off) ? ts[t - off] : 0;
        __syncthreads();
        ts[t] += u;
        __syncthreads();
    }
    int ex = ts[t] - s + blockoff[blockIdx.x];
    #pragma unroll
    for (int j = 0; j < 4; ++j) {
        if (base + j < n) {
            rowptr[base + j] = ex;
            cursor[base + j] = ex;
            inv_deg[base + j] = d[j] > 0 ? 1.0f / (float)d[j] : 0.0f;
            ex += d[j];
        }
    }
}

__global__ void fill_kernel(const int* __restrict__ src, const int* __restrict__ dst,
                            int* __restrict__ cursor, int* __restrict__ csr, int E) {
    int i = blockIdx.x * blockDim.x + threadIdx.x;
    if (i < E) {
        int p = atomicAdd(&cursor[dst[i]], 1);
        csr[p] = src[i];
    }
}

// fp32 -> bf16 (RTNE) convert, 8 elems/thread.
__global__ void f32_to_bf16(const float* __restrict__ in, uint16_t* __restrict__ out, int count) {
    int i = (blockIdx.x * blockDim.x + threadIdx.x) * 8;
    if (i >= count) return;
    float4 v0 = *(const float4*)(in + i);
    float4 v1 = *(const float4*)(in + i + 4);
    bf16x8 o;
    o[0] = (__bf16)v0.x; o[1] = (__bf16)v0.y; o[2] = (__bf16)v0.z; o[3] = (__bf16)v0.w;
    o[4] = (__bf16)v1.x; o[5] = (__bf16)v1.y; o[6] = (__bf16)v1.z; o[7] = (__bf16)v1.w;
    *(bf16x8*)(out + i) = o;
}

__device__ inline void addq(float* a, uint32_t u0, uint32_t u1, uint32_t u2, uint32_t u3) {
    uint32_t u[4] = {u0, u1, u2, u3};
    #pragma unroll
    for (int i = 0; i < 4; ++i) {
        a[2 * i]     += __uint_as_float(u[i] << 16);
        a[2 * i + 1] += __uint_as_float(u[i] & 0xffff0000u);
    }
}

// bf16 gather aggregation: C/8 lanes per node, 16B (8 bf16) per lane.
template<int C>
__global__ void agg_bf16(const uint16_t* __restrict__ hb, const int* __restrict__ rowptr,
                         const int* __restrict__ csr, const float* __restrict__ inv_deg,
                         float* __restrict__ aggs, int n) {
    constexpr int LPN = C / 8;
    constexpr int NPB = 256 / LPN;
    int node = blockIdx.x * NPB + (int)(threadIdx.x / LPN);
    if (node >= n) return;
    int sub = threadIdx.x % LPN;
    int b = rowptr[node], e = rowptr[node + 1];
    float acc[8] = {0.f, 0.f, 0.f, 0.f, 0.f, 0.f, 0.f, 0.f};
    const uint4* h4 = (const uint4*)hb;
    int k = b;
    for (; k + 3 < e; k += 4) {
        int s0 = csr[k], s1 = csr[k + 1], s2 = csr[k + 2], s3 = csr[k + 3];
        uint4 q0 = h4[(size_t)s0 * LPN + sub];
        uint4 q1 = h4[(size_t)s1 * LPN + sub];
        uint4 q2 = h4[(size_t)s2 * LPN + sub];
        uint4 q3 = h4[(size_t)s3 * LPN + sub];
        addq(acc, q0.x, q0.y, q0.z, q0.w);
        addq(acc, q1.x, q1.y, q1.z, q1.w);
        addq(acc, q2.x, q2.y, q2.z, q2.w);
        addq(acc, q3.x, q3.y, q3.z, q3.w);
    }
    for (; k < e; ++k) {
        uint4 q = h4[(size_t)csr[k] * LPN + sub];
        addq(acc, q.x, q.y, q.z, q.w);
    }
    float id = inv_deg[node];
    float4 r0 = make_float4(acc[0] * id, acc[1] * id, acc[2] * id, acc[3] * id);
    float4 r1 = make_float4(acc[4] * id, acc[5] * id, acc[6] * id, acc[7] * id);
    *(float4*)(aggs + (size_t)node * C + sub * 8) = r0;
    *(float4*)(aggs + (size_t)node * C + sub * 8 + 4) = r1;
}

// Exact fp32 gather (fallback if ws too small for bf16 copies).
template<int C>
__global__ void agg_kernel_n(const float* __restrict__ h, const int* __restrict__ rowptr,
                             const int* __restrict__ csr, const float* __restrict__ inv_deg,
                             float* __restrict__ aggs, int n) {
    constexpr int LPN = C / 4;
    constexpr int NPB = 256 / LPN;
    int node = blockIdx.x * NPB + (int)(threadIdx.x / LPN);
    if (node >= n) return;
    int sub = threadIdx.x % LPN;
    int b = rowptr[node], e = rowptr[node + 1];
    f32x4 a0 = (f32x4)(0.f), a1 = (f32x4)(0.f), a2 = (f32x4)(0.f), a3 = (f32x4)(0.f);
    const float4* h4 = (const float4*)h;
    int k = b;
    for (; k + 3 < e; k += 4) {
        int s0 = csr[k], s1 = csr[k + 1], s2 = csr[k + 2], s3 = csr[k + 3];
        float4 v0 = h4[(size_t)s0 * LPN + sub];
        float4 v1 = h4[(size_t)s1 * LPN + sub];
        float4 v2 = h4[(size_t)s2 * LPN + sub];
        float4 v3 = h4[(size_t)s3 * LPN + sub];
        a0 += (f32x4){v0.x, v0.y, v0.z, v0.w};
        a1 += (f32x4){v1.x, v1.y, v1.z, v1.w};
        a2 += (f32x4){v2.x, v2.y, v2.z, v2.w};
        a3 += (f32x4){v3.x, v3.y, v3.z, v3.w};
    }
    for (; k < e; ++k) {
        float4 v0 = h4[(size_t)csr[k] * LPN + sub];
        a0 += (f32x4){v0.x, v0.y, v0.z, v0.w};
    }
    f32x4 r = ((a0 + a1) + (a2 + a3)) * inv_deg[node];
    *(float4*)(aggs + (size_t)node * C + sub * 4) = (float4){r[0], r[1], r[2], r[3]};
}

// Pre-convert W = [Wl; Wr] into per-k-step bf16 hi/lo planes.
// Step s (BK=32): [hi 16KB][lo 16KB]; element (k,n) at byte n*64 + (k%32)*2.
__global__ void convert_w(const float* __restrict__ Wl, const float* __restrict__ Wr,
                          uint8_t* __restrict__ Wpre, int K1) {
    int n = threadIdx.x;
    int kbase = blockIdx.x * 4;
    bf16x4 hi4, lo4;
    #pragma unroll
    for (int j = 0; j < 4; ++j) {
        int k = kbase + j;
        float w = (k < K1) ? Wl[(size_t)k * 256 + n] : Wr[(size_t)(k - K1) * 256 + n];
        __bf16 h = (__bf16)w;
        __bf16 l = (__bf16)(w - (float)h);
        hi4[j] = h;
        lo4[j] = l;
    }
    int s = kbase >> 5;
    int kk = kbase & 31;
    uint32_t byte = (uint32_t)(n * 64 + kk * 2);
    *(bf16x4*)(Wpre + (size_t)s * 32768 + byte) = hi4;
    *(bf16x4*)(Wpre + (size_t)s * 32768 + 16384 + byte) = lo4;
}

__device__ inline uint16_t f2bf(float f) {
    __bf16 h = (__bf16)f;
    union { __bf16 b; uint16_t u; } c;
    c.b = h;
    return c.u;
}

// Fused GEMM: out = relu([A1 | A2] @ Wpre + bias). Split-bf16, 3 mfma/frag.
// Double-buffered A LDS + prefetch of A[s+1]/W[s+1] before MFMA[s]; 1 barrier/step.
template<int K1>
__global__ __launch_bounds__(256, 2)
void gemm_mfma(const float* __restrict__ A1, const float* __restrict__ A2,
               const uint8_t* __restrict__ Wpre, const float* __restrict__ bias,
               float* __restrict__ out, uint16_t* __restrict__ outb, int n) {
    constexpr int S1 = K1 / 32;
    constexpr int NT = 2 * S1;           // even, >= 8
    __shared__ __align__(16) uint8_t lds[2][8192];   // [buf][hi 4K | lo 4K]

    const int tid = threadIdx.x;
    const int l = tid & 63;
    const int w = tid >> 6;
    const int lr = l & 15;
    const int lg = l >> 4;
    const int row0 = blockIdx.x * 64;
    const int wn = w * 64;

    f32x4 acc[4][4];
    #pragma unroll
    for (int mt = 0; mt < 4; ++mt)
        #pragma unroll
        for (int nt = 0; nt < 4; ++nt)
            acc[mt][nt] = (f32x4)(0.f);

    uint32_t abyte[4], bbyte[4];
    #pragma unroll
    for (int mt = 0; mt < 4; ++mt) {
        int row = mt * 16 + lr;
        abyte[mt] = (uint32_t)(row * 64 + lg * 16) ^ (uint32_t)((lr & 7) << 4);
    }
    #pragma unroll
    for (int nt = 0; nt < 4; ++nt) {
        int nn = wn + nt * 16 + lr;
        bbyte[nt] = (uint32_t)(nn * 64 + lg * 16);
    }

    // A staging map: thread -> (row sr+p*32, k-quad sk), swizzled LDS byte
    const int sr = tid >> 3;          // 0..31
    const int sk = (tid & 7) * 4;     // 0,4,...,28
    uint32_t wbyte[2];
    #pragma unroll
    for (int p = 0; p < 2; ++p) {
        int r = sr + p * 32;
        wbyte[p] = (uint32_t)(r * 64 + sk * 2) ^ (uint32_t)((r & 7) << 4);
    }

    bf16x8 W0h[4], W0l[4], W1h[4], W1l[4];
    float4 areg[2];

    auto issueA = [&](int s) {
        const float* __restrict__ A = (s < S1) ? A1 : A2;
        int k0 = ((s < S1) ? s : s - S1) * 32;
        #pragma unroll
        for (int p = 0; p < 2; ++p) {
            int gr = row0 + sr + p * 32;
            areg[p] = (gr < n) ? *(const float4*)(A + (size_t)gr * K1 + k0 + sk)
                               : make_float4(0.f, 0.f, 0.f, 0.f);
        }
    };
    auto issueW = [&](int s, bf16x8 (&H)[4], bf16x8 (&L)[4]) {
        const uint8_t* __restrict__ Ws = Wpre + (size_t)s * 32768;
        #pragma unroll
        for (int nt = 0; nt < 4; ++nt) {
            H[nt] = *(const bf16x8*)(Ws + bbyte[nt]);
            L[nt] = *(const bf16x8*)(Ws + 16384 + bbyte[nt]);
        }
    };
    auto writeA = [&](uint8_t* buf) {
        #pragma unroll
        for (int p = 0; p < 2; ++p) {
            float vv[4] = {areg[p].x, areg[p].y, areg[p].z, areg[p].w};
            bf16x4 h4, l4;
            #pragma unroll
            for (int j = 0; j < 4; ++j) {
                __bf16 h = (__bf16)vv[j];
                h4[j] = h;
                l4[j] = (__bf16)(vv[j] - (float)h);
            }
            *(bf16x4*)(buf + wbyte[p]) = h4;
            *(bf16x4*)(buf + 4096 + wbyte[p]) = l4;
        }
    };
    auto compute = [&](const uint8_t* buf, bf16x8 (&H)[4], bf16x8 (&L)[4]) {
        #pragma unroll
        for (int mt = 0; mt < 4; ++mt) {
            bf16x8 ahi = *(const bf16x8*)(buf + abyte[mt]);
            bf16x8 alo = *(const bf16x8*)(buf + 4096 + abyte[mt]);
            #pragma unroll
            for (int nt = 0; nt < 4; ++nt) {
                acc[mt][nt] = __builtin_amdgcn_mfma_f32_16x16x32_bf16(ahi, H[nt], acc[mt][nt], 0, 0, 0);
                acc[mt][nt] = __builtin_amdgcn_mfma_f32_16x16x32_bf16(alo, H[nt], acc[mt][nt], 0, 0, 0);
                acc[mt][nt] = __builtin_amdgcn_mfma_f32_16x16x32_bf16(ahi, L[nt], acc[mt][nt], 0, 0, 0);
            }
        }
    };

    // prologue: stage step 0 into buf0, W0 into set0
    issueA(0);
    issueW(0, W0h, W0l);
    writeA(lds[0]);
    __syncthreads();

    // main loop: pairs (even uses buf0/W0, odd uses buf1/W1); last two peeled.
    #pragma unroll 1
    for (int s = 0; s < NT - 2; s += 2) {
        issueA(s + 1);
        issueW(s + 1, W1h, W1l);
        compute(lds[0], W0h, W0l);
        writeA(lds[1]);
        __syncthreads();

        issueA(s + 2);
        issueW(s + 2, W0h, W0l);
        compute(lds[1], W1h, W1l);
        writeA(lds[0]);
        __syncthreads();
    }
    // s = NT-2 (even)
    issueA(NT - 1);
    issueW(NT - 1, W1h, W1l);
    compute(lds[0], W0h, W0l);
    writeA(lds[1]);
    __syncthreads();
    // s = NT-1 (odd, last)
    compute(lds[1], W1h, W1l);

    // epilogue: D row = mt*16 + lg*4 + rr, col = wn + nt*16 + lr
    #pragma unroll
    for (int nt = 0; nt < 4; ++nt) {
        int col = wn + nt * 16 + lr;
        float bv = bias[col];
        #pragma unroll
        for (int mt = 0; mt < 4; ++mt) {
            #pragma unroll
            for (int rr = 0; rr < 4; ++rr) {
                int grow = row0 + mt * 16 + lg * 4 + rr;
                if (grow < n) {
                    float v = fmaxf(acc[mt][nt][rr] + bv, 0.f);
                    out[(size_t)grow * 256 + col] = v;
                    if (outb) outb[(size_t)grow * 256 + col] = f2bf(v);
                }
            }
        }
    }
}

extern "C" void kernel_launch(void* const* d_in, const int* in_sizes, int n_in,
                              void* d_out, int out_size, void* d_ws, size_t ws_size,
                              hipStream_t stream) {
    const float* x   = (const float*)d_in[0];
    const int* edge  = (const int*)d_in[1];
    const float* Wl0 = (const float*)d_in[2];
    const float* bl0 = (const float*)d_in[3];
    const float* Wr0 = (const float*)d_in[4];
    const float* Wl1 = (const float*)d_in[5];
    const float* bl1 = (const float*)d_in[6];
    const float* Wr1 = (const float*)d_in[7];
    const float* Wl2 = (const float*)d_in[8];
    const float* bl2 = (const float*)d_in[9];
    const float* Wr2 = (const float*)d_in[10];

    int n = in_sizes[0] / 128;   // 50000
    int E = in_sizes[1] / 2;     // 800000
    const int* src = edge;
    const int* dst = edge + E;

    char* wptr = (char*)d_ws;
    auto alloc = [&](size_t bytes) { char* p = wptr; wptr += align_up(bytes, 256); return p; };
    int*     deg    = (int*)alloc((size_t)n * 4);
    int*     rowptr = (int*)alloc(((size_t)n + 1) * 4);
    int*     cursor = (int*)alloc((size_t)n * 4);
    int*     csr    = (int*)alloc((size_t)E * 4);
    float*   invd   = (float*)alloc((size_t)n * 4);
    int*     bsums  = (int*)alloc(256 * 4);
    int*     boff   = (int*)alloc(256 * 4);
    uint8_t* Wp0    = (uint8_t*)alloc(8 * 32768);
    uint8_t* Wp1    = (uint8_t*)alloc(16 * 32768);
    uint8_t* Wp2    = (uint8_t*)alloc(16 * 32768);
    float*   aggs   = (float*)alloc((size_t)n * 256 * 4);
    float*   h1     = (float*)alloc((size_t)n * 256 * 4);
    uint16_t* xb_h1b = (uint16_t*)alloc((size_t)n * 256 * 2);  // xb shares with h1b
    uint16_t* h0b    = (uint16_t*)alloc((size_t)n * 256 * 2);
    float*   h0     = (float*)d_out;

    bool use_bf16 = ((size_t)(wptr - (char*)d_ws) <= ws_size);
    uint16_t* xb  = xb_h1b;
    uint16_t* h1b = xb_h1b;

    int NB = (n + 1023) / 1024;
    hipMemsetAsync(deg, 0, (size_t)n * 4, stream);
    deg_kernel<<<(E + 255) / 256, 256, 0, stream>>>(dst, deg, E);
    scan_a<<<NB, 256, 0, stream>>>(deg, bsums, n);
    scan_b<<<1, 256, 0, stream>>>(bsums, boff, NB, rowptr + n);
    scan_c<<<NB, 256, 0, stream>>>(deg, boff, rowptr, cursor, invd, n);
    fill_kernel<<<(E + 255) / 256, 256, 0, stream>>>(src, dst, cursor, csr, E);

    convert_w<<<2 * 128 / 4, 256, 0, stream>>>(Wl0, Wr0, Wp0, 128);
    convert_w<<<2 * 256 / 4, 256, 0, stream>>>(Wl1, Wr1, Wp1, 256);
    convert_w<<<2 * 256 / 4, 256, 0, stream>>>(Wl2, Wr2, Wp2, 256);

    int gemm_grid = (n + 63) / 64;
    if (use_bf16) {
        int cx = n * 128;
        f32_to_bf16<<<(cx / 8 + 255) / 256, 256, 0, stream>>>(x, xb, cx);
        // layer 0: C=128 -> 256
        agg_bf16<128><<<(n + 15) / 16, 256, 0, stream>>>(xb, rowptr, csr, invd, aggs, n);
        gemm_mfma<128><<<gemm_grid, 256, 0, stream>>>(aggs, x, Wp0, bl0, h0, h0b, n);
        // layer 1: 256 -> 256
        agg_bf16<256><<<(n + 7) / 8, 256, 0, stream>>>(h0b, rowptr, csr, invd, aggs, n);
        gemm_mfma<256><<<gemm_grid, 256, 0, stream>>>(aggs, h0, Wp1, bl1, h1, h1b, n);
        // layer 2: 256 -> 256
        agg_bf16<256><<<(n + 7) / 8, 256, 0, stream>>>(h1b, rowptr, csr, invd, aggs, n);
        gemm_mfma<256><<<gemm_grid, 256, 0, stream>>>(aggs, h1, Wp2, bl2, (float*)d_out, (uint16_t*)nullptr, n);
    } else {
        agg_kernel_n<128><<<(n + 7) / 8, 256, 0, stream>>>(x, rowptr, csr, invd, aggs, n);
        gemm_mfma<128><<<gemm_grid, 256, 0, stream>>>(aggs, x, Wp0, bl0, h0, (uint16_t*)nullptr, n);
        agg_kernel_n<256><<<(n + 3) / 4, 256, 0, stream>>>(h0, rowptr, csr, invd, aggs, n);
        gemm_mfma<256><<<gemm_grid, 256, 0, stream>>>(aggs, h0, Wp1, bl1, h1, (uint16_t*)nullptr, n);
        agg_kernel_n<256><<<(n + 3) / 4, 256, 0, stream>>>(h1, rowptr, csr, invd, aggs, n);
        gemm_mfma<256><<<gemm_grid, 256, 0, stream>>>(aggs, h1, Wp2, bl2, (float*)d_out, (uint16_t*)nullptr, n);
    }
}